// Round 6
// baseline (744.150 us; speedup 1.0000x reference)
//
#include <hip/hip_runtime.h>
#include <hip/hip_bf16.h>
#include <math.h>

#define D 64
#define CDIM 128
#define NL 5
#define NB 8
#define HID 256
#define ODIM 1472      // D*(3*NB-1)
#define PPD 23
#define PPDP 24        // padded params per dim
#define NPAD 1536      // D*PPDP
#define NTRI 2016
#define BATCH 32768

// fused GEMM3+spline+LU geometry
#define FROWS 32       // batch rows per block
#define NCH 4          // dim chunks (16 dims each)
#define CPC 384        // param cols per chunk
#define HPAD 264       // hh2_s row stride (u16): 528B = 132 dwords = 4 mod 32 -> bank-balanced
#define PPAD 392       // params_s row stride (u16): 784B = 196 dwords = 4 mod 32 -> balanced

typedef unsigned short u16;
typedef __attribute__((ext_vector_type(8))) short bf16x8;
typedef __attribute__((ext_vector_type(8))) unsigned short u16x8;
typedef __attribute__((ext_vector_type(4))) float f32x4;
typedef __attribute__((ext_vector_type(8))) float f32x8;

__device__ __forceinline__ float softplusf(float x) {
    return fmaxf(x, 0.0f) + log1pf(__expf(-fabsf(x)));
}
__device__ __forceinline__ float softplus_fast(float x) {
    return fmaxf(x, 0.0f) + __logf(1.0f + __expf(-fabsf(x)));
}
__device__ __forceinline__ float frcp(float x) { return __builtin_amdgcn_rcpf(x); }
__device__ __forceinline__ u16 f2bf(float f) {
    __hip_bfloat16 h = __float2bfloat16(f);
    return *reinterpret_cast<u16*>(&h);
}
__device__ __forceinline__ float bf2f(u16 u) {
    return __uint_as_float(((unsigned int)u) << 16);
}

// global->LDS direct 16B load; LDS dest is wave-uniform base + lane*16.
__device__ __forceinline__ void gload16(const u16* g, const u16* s) {
    __builtin_amdgcn_global_load_lds(
        (const __attribute__((address_space(1))) unsigned int*)(unsigned long long)(uintptr_t)g,
        (__attribute__((address_space(3))) unsigned int*)(unsigned int)(uintptr_t)s,
        16, 0, 0);
}

// bijective XCD-chunked swizzle (m204)
__device__ __forceinline__ int xcd_swz(int bid, int nwg) {
    int q = nwg >> 3, r = nwg & 7;
    int xcd = bid & 7, idx = bid >> 3;
    return (xcd < r ? xcd * (q + 1) : r * (q + 1) + (xcd - r) * q) + idx;
}

// ---------------- prep: context -> bf16 --------------------------------------
__global__ void cvt_ctx(const float* __restrict__ c, u16* __restrict__ o) {
    int i = blockIdx.x * 256 + threadIdx.x;
    if (i < BATCH * CDIM) o[i] = f2bf(c[i]);
}

// ---------------- prep: W1t/W2t transposed bf16 ------------------------------
__global__ void prep_w12(const float* __restrict__ W1, const float* __restrict__ W2,
                         u16* __restrict__ W1t, u16* __restrict__ W2t) {
    int i = blockIdx.x * 256 + threadIdx.x;
    if (i < NL * HID * CDIM) {   // W1t[l][n][k] = W1[l][k][n]
        int k = i % CDIM; int n = (i / CDIM) % HID; int l = i / (CDIM * HID);
        W1t[i] = f2bf(W1[(l * CDIM + k) * HID + n]);
    }
    if (i < NL * HID * HID) {    // W2t[l][n][k] = W2[l][k][n]
        int k = i % HID; int n = (i / HID) % HID; int l = i / (HID * HID);
        W2t[i] = f2bf(W2[(l * HID + k) * HID + n]);
    }
}

// ---------------- prep: W3t padded/transposed + padded bias ------------------
__global__ void prep_w3(const float* __restrict__ W3, const float* __restrict__ b3,
                        u16* __restrict__ W3t, float* __restrict__ b3p) {
    int i = blockIdx.x * 256 + threadIdx.x;
    if (i < NL * NPAD * HID) {   // W3t[l][n][k], n = d*24+p
        int k = i % HID; int n = (i / HID) % NPAD; int l = i / (HID * NPAD);
        int dd = n / PPDP, p = n % PPDP;
        W3t[i] = (p < PPD) ? f2bf(W3[(l * HID + k) * ODIM + dd * PPD + p]) : (u16)0;
    }
    if (i < NL * NPAD) {
        int n = i % NPAD; int l = i / NPAD;
        int dd = n / PPDP, p = n % PPDP;
        b3p[i] = (p < PPD) ? b3[l * ODIM + dd * PPD + p] : 0.0f;
    }
}

// ---------------- precompute: A_t = (L@U)^T per layer, total LU logdet -------
__global__ void lu_prep(const float* __restrict__ lower_e,
                        const float* __restrict__ upper_e,
                        const float* __restrict__ udiag,
                        float* __restrict__ At, float* __restrict__ lu_const) {
    int l = blockIdx.x;
    int t = threadIdx.x;
    __shared__ float Ls[D * D];
    __shared__ float Us[D * D];
    __shared__ float red[4];
    for (int idx = t; idx < D * D; idx += 256) {
        int i = idx >> 6, j = idx & 63;
        float lv;
        if (i == j)      lv = 1.0f;
        else if (i > j)  lv = lower_e[l * NTRI + (i * (i - 1)) / 2 + j];
        else             lv = 0.0f;
        Ls[idx] = lv;
        float uv;
        if (i == j)      uv = softplusf(udiag[l * D + i]) + 0.001f;
        else if (j > i)  uv = upper_e[l * NTRI + i * (D - 1) - (i * (i - 1)) / 2 + (j - i - 1)];
        else             uv = 0.0f;
        Us[idx] = uv;
    }
    __syncthreads();
    for (int idx = t; idx < D * D; idx += 256) {
        int i = idx >> 6, j = idx & 63;
        float acc = 0.0f;
        int km = min(i, j);
        for (int k = 0; k <= km; ++k) acc += Ls[i * D + k] * Us[k * D + j];
        At[(l * D + j) * D + i] = acc;   // transposed store
    }
    if (l == 0) {
        float s = 0.0f;
        for (int i = t; i < NL * D; i += 256)
            s += __logf(softplusf(udiag[i]) + 0.001f);
#pragma unroll
        for (int off = 32; off; off >>= 1) s += __shfl_xor(s, off);
        if ((t & 63) == 0) red[t >> 6] = s;
        __syncthreads();
        if (t == 0) lu_const[0] = red[0] + red[1] + red[2] + red[3];
    }
}

// ---------------- init: copy x, zero logdet ----------------------------------
__global__ void init_kernel(const float* __restrict__ inp, float* __restrict__ x,
                            float* __restrict__ logdet) {
    int i = blockIdx.x * 256 + threadIdx.x;
    if (i < BATCH * D) x[i] = inp[i];
    if (i < BATCH) logdet[i] = 0.0f;
}

// ---------------- MFMA GEMM (for GEMM1/GEMM2): C = relu(A @ Bt^T + bias) -----
template<int RELU>
__global__ __launch_bounds__(256) void gemm_bf16(
    const u16* __restrict__ A, const u16* __restrict__ Bt,
    const float* __restrict__ bias, u16* __restrict__ Cv,
    int N, int K, int ncol)
{
    __shared__ u16 lds[16384];
    const int t = threadIdx.x;
    const int w = t >> 6, l = t & 63;
    const int wm = w >> 1, wn = w & 1;
    const int wg = xcd_swz(blockIdx.x, gridDim.x);
    const size_t m0 = (size_t)(wg / ncol) * 128;
    const int n0 = (wg % ncol) * 128;
    const int lrow = l & 15, lk = l >> 4;
    const int srow = l >> 3, sslot = l & 7;

    f32x4 acc[4][4] = {};

    for (int k0 = 0; k0 < K; k0 += 64) {
#pragma unroll
        for (int q = 0; q < 4; ++q) {
            int c = q * 4 + w;
            int row = c * 8 + srow;
            int slog = sslot ^ (row & 7);
            gload16(A + (m0 + row) * K + k0 + slog * 8, &lds[c * 512]);
        }
#pragma unroll
        for (int q = 0; q < 4; ++q) {
            int c = q * 4 + w;
            int row = c * 8 + srow;
            int slog = sslot ^ (row & 7);
            gload16(Bt + (size_t)(n0 + row) * K + k0 + slog * 8, &lds[8192 + c * 512]);
        }
        __syncthreads();
#pragma unroll
        for (int ks = 0; ks < 2; ++ks) {
            bf16x8 a[4], b[4];
#pragma unroll
            for (int mf = 0; mf < 4; ++mf) {
                int row = wm * 64 + mf * 16 + lrow;
                int slot = (ks * 4 + lk) ^ (row & 7);
                a[mf] = *(const bf16x8*)&lds[row * 64 + slot * 8];
            }
#pragma unroll
            for (int nf = 0; nf < 4; ++nf) {
                int row = wn * 64 + nf * 16 + lrow;
                int slot = (ks * 4 + lk) ^ (row & 7);
                b[nf] = *(const bf16x8*)&lds[8192 + row * 64 + slot * 8];
            }
#pragma unroll
            for (int mf = 0; mf < 4; ++mf)
#pragma unroll
                for (int nf = 0; nf < 4; ++nf)
                    acc[mf][nf] = __builtin_amdgcn_mfma_f32_16x16x32_bf16(
                        a[mf], b[nf], acc[mf][nf], 0, 0, 0);
        }
        __syncthreads();
    }
#pragma unroll
    for (int nf = 0; nf < 4; ++nf) {
        int col = n0 + wn * 64 + nf * 16 + lrow;
        float bv = bias[col];
#pragma unroll
        for (int mf = 0; mf < 4; ++mf) {
            size_t rbase = m0 + wm * 64 + mf * 16 + lk * 4;
#pragma unroll
            for (int i = 0; i < 4; ++i) {
                float v = acc[mf][nf][i] + bv;
                if (RELU) v = fmaxf(v, 0.0f);
                Cv[(rbase + i) * N + col] = f2bf(v);
            }
        }
    }
}

// ---------------- spline helpers (register-only) -----------------------------
__device__ __forceinline__ f32x8 cumb(f32x8 p) {
    float m = fmaxf(fmaxf(fmaxf(p[0], p[1]), fmaxf(p[2], p[3])),
                    fmaxf(fmaxf(p[4], p[5]), fmaxf(p[6], p[7])));
    f32x8 e;
    float s = 0.0f;
#pragma unroll
    for (int i = 0; i < 8; ++i) { e[i] = __expf(p[i] - m); s += e[i]; }
    float tt = 0.992f * frcp(s);
    f32x8 c;
    float run = 0.0f;
#pragma unroll
    for (int i = 0; i < 7; ++i) {
        run = fmaf(tt, e[i], run + 0.001f);
        c[i] = fmaf(10.0f, run, -5.0f);
    }
    c[7] = 5.0f;
    return c;
}

__device__ __forceinline__ void rqs_v(float xv, f32x8 uw, f32x8 uh, f32x8 ud,
                                      float& yo, float& ldo) {
    f32x8 cw = cumb(uw);
    f32x8 ch = cumb(uh);
    f32x8 dv;
#pragma unroll
    for (int i = 0; i < 7; ++i) dv[i] = 0.001f + softplus_fast(ud[i]);
    float xc = fminf(fmaxf(xv, -5.0f), 5.0f);
    float icw = -5.0f, icw1 = cw[0], ich = -5.0f, ich1 = ch[0];
    float d0 = 1.0f, d1 = dv[0];
#pragma unroll
    for (int k = 1; k < 8; ++k) {
        bool sel = (xc >= cw[k - 1]);
        icw  = sel ? cw[k - 1] : icw;
        icw1 = sel ? cw[k]     : icw1;
        ich  = sel ? ch[k - 1] : ich;
        ich1 = sel ? ch[k]     : ich1;
        d0   = sel ? dv[k - 1] : d0;
        d1   = sel ? ((k < 7) ? dv[k] : 1.0f) : d1;
    }
    float iw  = icw1 - icw;
    float ih  = ich1 - ich;
    float riw = frcp(iw);
    float dlt = ih * riw;
    float th  = (xc - icw) * riw;
    float omt = 1.0f - th;
    float tomt = th * omt;
    float numer = ih * (dlt * th * th + d0 * tomt);
    float den = dlt + (d0 + d1 - 2.0f * dlt) * tomt;
    float rden = frcp(den);
    float outv = ich + numer * rden;
    float dnum = dlt * dlt * (d1 * th * th + 2.0f * dlt * tomt + d0 * omt * omt);
    float ld = __logf(dnum * rden * rden);
    bool inside = (xv >= -5.0f) && (xv <= 5.0f);
    yo  = inside ? outv : xv;
    ldo = inside ? ld : 0.0f;
}

// ---------------- FUSED: GEMM3 (operand-swapped MFMA) + spline + LU ----------
// Block: 32 batch rows, 512 threads (8 waves). Per dim-chunk (16 dims, 384 cols):
//   MFMA: wave w owns cols w*48..w*48+47 (3 M-frags), all 32 rows (2 N-frags).
//   Operand swap: mfma(Wfrag, Hfrag) -> lane holds 4 CONSECUTIVE param cols for
//   one batch row -> bias+pack -> one 8B LDS write into row-padded params LDS.
//   Then spline (1 (row,dim) pair per thread) straight from LDS. Params never
//   touch HBM (was 200 MB/layer round trip).
__global__ __launch_bounds__(512, 4) void gemm3_spline_lu(
    const u16* __restrict__ hh2,     // [BATCH][256] bf16
    const u16* __restrict__ W3t,     // [1536][256] bf16 (layer slab)
    const float* __restrict__ b3p,   // [1536] padded bias (layer slab)
    const float* __restrict__ At, const float* __restrict__ lu_bias,
    float* __restrict__ x, float* __restrict__ logdet, int lay)
{
    __shared__ u16 hh2_s[FROWS * HPAD];      // 16896 B
    __shared__ u16 params_s[FROWS * PPAD];   // 25088 B
    __shared__ float y_s[FROWS * 65];        // 8320 B (pad 65: bank-free)
    __shared__ float ld_s[FROWS];
    const int t = threadIdx.x;
    const int w = t >> 6;
    const int ln = t & 63;
    const int lr = ln & 15, lk = ln >> 4;
    const int rbase = blockIdx.x * FROWS;

    // stage hh2 tile (32 rows x 256 cols bf16 = 8192 u16) into padded LDS.
    // BUGFIX (round 5 NaN): each thread now loads 16 u16 (2x bf16x8), covering
    // the full row; the old single-bf16x8 version left half of hh2_s garbage.
    {
        int row = t >> 4, k0 = (t & 15) * 16;
        const u16* src = hh2 + (size_t)(rbase + row) * HID + k0;
        bf16x8 v0 = *(const bf16x8*)src;
        bf16x8 v1 = *(const bf16x8*)(src + 8);
        *(bf16x8*)&hh2_s[row * HPAD + k0] = v0;
        *(bf16x8*)&hh2_s[row * HPAD + k0 + 8] = v1;
    }
    if (t < FROWS) ld_s[t] = 0.0f;
    __syncthreads();

    float ld_acc = 0.0f;
    const int sr = t & 31, sd = t >> 5;   // spline map: row, dim-in-chunk

    for (int ch = 0; ch < NCH; ++ch) {
        // ---- MFMA: params^T chunk; W as A-operand, H as B-operand ----
        f32x4 acc[3][2] = {};
        const u16* wbase = W3t + (size_t)(ch * CPC + w * 48 + lr) * HID + lk * 8;
#pragma unroll 2
        for (int ks = 0; ks < 8; ++ks) {
            bf16x8 hf0 = *(const bf16x8*)&hh2_s[lr * HPAD + ks * 32 + lk * 8];
            bf16x8 hf1 = *(const bf16x8*)&hh2_s[(16 + lr) * HPAD + ks * 32 + lk * 8];
#pragma unroll
            for (int mf = 0; mf < 3; ++mf) {
                bf16x8 wf = *(const bf16x8*)(wbase + mf * 16 * HID + ks * 32);
                acc[mf][0] = __builtin_amdgcn_mfma_f32_16x16x32_bf16(wf, hf0, acc[mf][0], 0, 0, 0);
                acc[mf][1] = __builtin_amdgcn_mfma_f32_16x16x32_bf16(wf, hf1, acc[mf][1], 0, 0, 0);
            }
        }
        __syncthreads();   // prev spline done reading params_s; MFMA acc ready

        // ---- epilogue: bias + pack 4 cols -> 8B LDS write ----
        {
            const float* bb = b3p + ch * CPC + w * 48 + 4 * lk;
#pragma unroll
            for (int mf = 0; mf < 3; ++mf) {
                float4 bv = *(const float4*)(bb + mf * 16);
#pragma unroll
                for (int rf = 0; rf < 2; ++rf) {
                    f32x4 v = acc[mf][rf];
                    unsigned int lo = (unsigned int)f2bf(v[0] + bv.x)
                                    | ((unsigned int)f2bf(v[1] + bv.y) << 16);
                    unsigned int hi = (unsigned int)f2bf(v[2] + bv.z)
                                    | ((unsigned int)f2bf(v[3] + bv.w) << 16);
                    uint2 pv; pv.x = lo; pv.y = hi;
                    int r = rf * 16 + lr;
                    int cbase = w * 48 + mf * 16 + 4 * lk;
                    *(uint2*)&params_s[r * PPAD + cbase] = pv;
                }
            }
        }
        __syncthreads();

        // ---- spline: 1 (row, dim) pair per thread ----
        {
            const u16x8* pp = (const u16x8*)&params_s[sr * PPAD + sd * PPDP];
            u16x8 q0 = pp[0], q1 = pp[1], q2 = pp[2];
            f32x8 uw, uh, ud;
#pragma unroll
            for (int j = 0; j < 8; ++j) {
                uw[j] = bf2f(q0[j]);
                uh[j] = bf2f(q1[j]);
                ud[j] = bf2f(q2[j]);
            }
            int dg = ch * 16 + sd;
            float xv = x[(size_t)(rbase + sr) * D + dg];
            float y, ldv;
            rqs_v(xv, uw, uh, ud, y, ldv);
            y_s[sr * 65 + dg] = y;
            ld_acc += ldv;
        }
        // no barrier: next MFMA phase doesn't touch params_s; the pre-epilogue
        // barrier guarantees all waves finished this spline before overwrite.
    }

    atomicAdd(&ld_s[sr], ld_acc);
    __syncthreads();
    if (t < FROWS) logdet[rbase + t] += ld_s[t];

    // ---- LU: x_new[r][i] = sum_j y[r][j]*A[i][j] + bias[i] ----
#pragma unroll
    for (int p = 0; p < 4; ++p) {
        int idx = p * 512 + t;
        int r = idx >> 6, i = idx & 63;
        float acc2 = lu_bias[lay * D + i];
        const float* ap = At + (size_t)lay * D * D + i;
#pragma unroll 8
        for (int j = 0; j < D; ++j)
            acc2 = fmaf(y_s[r * 65 + j], ap[j * D], acc2);
        x[(size_t)(rbase + r) * D + i] = acc2;
    }
}

// ---------------- final: out = base + logdet ---------------------------------
__global__ void final_kernel(const float* __restrict__ x,
                             const float* __restrict__ logdet,
                             const float* __restrict__ lu_const,
                             float* __restrict__ out) {
    int t = threadIdx.x;
    int b = blockIdx.x * 4 + (t >> 6);
    int d = t & 63;
    float v = x[(size_t)b * D + d];
    float s = v * v;
#pragma unroll
    for (int off = 32; off; off >>= 1) s += __shfl_xor(s, off);
    if (d == 0)
        out[b] = logdet[b] + lu_const[0] - 0.5f * s - 0.5f * 64.0f * 1.8378770664093453f;
}

extern "C" void kernel_launch(void* const* d_in, const int* in_sizes, int n_in,
                              void* d_out, int out_size, void* d_ws, size_t ws_size,
                              hipStream_t stream) {
    const float* inputs  = (const float*)d_in[0];
    const float* context = (const float*)d_in[1];
    const float* W1      = (const float*)d_in[2];
    const float* b1      = (const float*)d_in[3];
    const float* W2      = (const float*)d_in[4];
    const float* b2      = (const float*)d_in[5];
    const float* W3      = (const float*)d_in[6];
    const float* b3      = (const float*)d_in[7];
    const float* lu_bias = (const float*)d_in[8];
    const float* lower_e = (const float*)d_in[9];
    const float* upper_e = (const float*)d_in[10];
    const float* udiag   = (const float*)d_in[11];
    float* out = (float*)d_out;

    char* p = (char*)d_ws;
    auto alloc = [&](size_t bytes) { void* r = p; p += (bytes + 255) & ~(size_t)255; return r; };
    float* x        = (float*)alloc((size_t)BATCH * D * 4);
    float* logdet   = (float*)alloc((size_t)BATCH * 4);
    float* At       = (float*)alloc((size_t)NL * D * D * 4);
    float* lu_const = (float*)alloc(256);
    u16*   ctx_bf   = (u16*)alloc((size_t)BATCH * CDIM * 2);
    u16*   hh1      = (u16*)alloc((size_t)BATCH * HID * 2);
    u16*   hh2      = (u16*)alloc((size_t)BATCH * HID * 2);
    u16*   W1t      = (u16*)alloc((size_t)NL * HID * CDIM * 2);
    u16*   W2t      = (u16*)alloc((size_t)NL * HID * HID * 2);
    u16*   W3t      = (u16*)alloc((size_t)NL * NPAD * HID * 2);
    float* b3p      = (float*)alloc((size_t)NL * NPAD * 4);

    cvt_ctx<<<(BATCH * CDIM + 255) / 256, 256, 0, stream>>>(context, ctx_bf);
    prep_w12<<<(NL * HID * HID + 255) / 256, 256, 0, stream>>>(W1, W2, W1t, W2t);
    prep_w3<<<(NL * NPAD * HID + 255) / 256, 256, 0, stream>>>(W3, b3, W3t, b3p);
    lu_prep<<<NL, 256, 0, stream>>>(lower_e, upper_e, udiag, At, lu_const);
    init_kernel<<<(BATCH * D + 255) / 256, 256, 0, stream>>>(inputs, x, logdet);

    for (int lay = 0; lay < NL; ++lay) {
        gemm_bf16<1><<<(BATCH / 128) * 2, 256, 0, stream>>>(
            ctx_bf, W1t + (size_t)lay * HID * CDIM, b1 + lay * HID, hh1, HID, CDIM, 2);
        gemm_bf16<1><<<(BATCH / 128) * 2, 256, 0, stream>>>(
            hh1, W2t + (size_t)lay * HID * HID, b2 + lay * HID, hh2, HID, HID, 2);
        gemm3_spline_lu<<<BATCH / FROWS, 512, 0, stream>>>(
            hh2, W3t + (size_t)lay * NPAD * HID, b3p + (size_t)lay * NPAD,
            At, lu_bias, x, logdet, lay);
    }
    final_kernel<<<BATCH / 4, 256, 0, stream>>>(x, logdet, lu_const, out);
}

// Round 7
// 588.021 us; speedup vs baseline: 1.2655x; 1.2655x over previous
//
#include <hip/hip_runtime.h>
#include <hip/hip_bf16.h>
#include <math.h>

#define D 64
#define CDIM 128
#define NL 5
#define NB 8
#define HID 256
#define ODIM 1472      // D*(3*NB-1)
#define PPD 23
#define PPDP 24        // padded params per dim
#define NPAD 1536      // D*PPDP
#define NTRI 2016
#define BATCH 32768

// fused GEMM3+spline+LU geometry
#define FROWS 64       // batch rows per block
#define NCH 4          // dim chunks (16 dims each)
#define CPC 384        // param cols per chunk
#define PPAD 392       // params_s row stride (u16)

typedef unsigned short u16;
typedef __attribute__((ext_vector_type(8))) short bf16x8;
typedef __attribute__((ext_vector_type(8))) unsigned short u16x8;
typedef __attribute__((ext_vector_type(4))) float f32x4;
typedef __attribute__((ext_vector_type(8))) float f32x8;

__device__ __forceinline__ float softplusf(float x) {
    return fmaxf(x, 0.0f) + log1pf(__expf(-fabsf(x)));
}
__device__ __forceinline__ float softplus_fast(float x) {
    return fmaxf(x, 0.0f) + __logf(1.0f + __expf(-fabsf(x)));
}
__device__ __forceinline__ float frcp(float x) { return __builtin_amdgcn_rcpf(x); }
__device__ __forceinline__ u16 f2bf(float f) {
    __hip_bfloat16 h = __float2bfloat16(f);
    return *reinterpret_cast<u16*>(&h);
}
__device__ __forceinline__ float bf2f(u16 u) {
    return __uint_as_float(((unsigned int)u) << 16);
}

// global->LDS direct 16B load; LDS dest is wave-uniform base + lane*16.
__device__ __forceinline__ void gload16(const u16* g, const u16* s) {
    __builtin_amdgcn_global_load_lds(
        (const __attribute__((address_space(1))) unsigned int*)(unsigned long long)(uintptr_t)g,
        (__attribute__((address_space(3))) unsigned int*)(unsigned int)(uintptr_t)s,
        16, 0, 0);
}

// bijective XCD-chunked swizzle (m204)
__device__ __forceinline__ int xcd_swz(int bid, int nwg) {
    int q = nwg >> 3, r = nwg & 7;
    int xcd = bid & 7, idx = bid >> 3;
    return (xcd < r ? xcd * (q + 1) : r * (q + 1) + (xcd - r) * q) + idx;
}

// ---------------- prep: context -> bf16 --------------------------------------
__global__ void cvt_ctx(const float* __restrict__ c, u16* __restrict__ o) {
    int i = blockIdx.x * 256 + threadIdx.x;
    if (i < BATCH * CDIM) o[i] = f2bf(c[i]);
}

// ---------------- prep: W1t/W2t transposed bf16 ------------------------------
__global__ void prep_w12(const float* __restrict__ W1, const float* __restrict__ W2,
                         u16* __restrict__ W1t, u16* __restrict__ W2t) {
    int i = blockIdx.x * 256 + threadIdx.x;
    if (i < NL * HID * CDIM) {   // W1t[l][n][k] = W1[l][k][n]
        int k = i % CDIM; int n = (i / CDIM) % HID; int l = i / (CDIM * HID);
        W1t[i] = f2bf(W1[(l * CDIM + k) * HID + n]);
    }
    if (i < NL * HID * HID) {    // W2t[l][n][k] = W2[l][k][n]
        int k = i % HID; int n = (i / HID) % HID; int l = i / (HID * HID);
        W2t[i] = f2bf(W2[(l * HID + k) * HID + n]);
    }
}

// ---------------- prep: W3t padded/transposed + padded bias ------------------
__global__ void prep_w3(const float* __restrict__ W3, const float* __restrict__ b3,
                        u16* __restrict__ W3t, float* __restrict__ b3p) {
    int i = blockIdx.x * 256 + threadIdx.x;
    if (i < NL * NPAD * HID) {   // W3t[l][n][k], n = d*24+p
        int k = i % HID; int n = (i / HID) % NPAD; int l = i / (HID * NPAD);
        int dd = n / PPDP, p = n % PPDP;
        W3t[i] = (p < PPD) ? f2bf(W3[(l * HID + k) * ODIM + dd * PPD + p]) : (u16)0;
    }
    if (i < NL * NPAD) {
        int n = i % NPAD; int l = i / NPAD;
        int dd = n / PPDP, p = n % PPDP;
        b3p[i] = (p < PPD) ? b3[l * ODIM + dd * PPD + p] : 0.0f;
    }
}

// ---------------- precompute: A_t = (L@U)^T per layer, total LU logdet -------
__global__ void lu_prep(const float* __restrict__ lower_e,
                        const float* __restrict__ upper_e,
                        const float* __restrict__ udiag,
                        float* __restrict__ At, float* __restrict__ lu_const) {
    int l = blockIdx.x;
    int t = threadIdx.x;
    __shared__ float Ls[D * D];
    __shared__ float Us[D * D];
    __shared__ float red[4];
    for (int idx = t; idx < D * D; idx += 256) {
        int i = idx >> 6, j = idx & 63;
        float lv;
        if (i == j)      lv = 1.0f;
        else if (i > j)  lv = lower_e[l * NTRI + (i * (i - 1)) / 2 + j];
        else             lv = 0.0f;
        Ls[idx] = lv;
        float uv;
        if (i == j)      uv = softplusf(udiag[l * D + i]) + 0.001f;
        else if (j > i)  uv = upper_e[l * NTRI + i * (D - 1) - (i * (i - 1)) / 2 + (j - i - 1)];
        else             uv = 0.0f;
        Us[idx] = uv;
    }
    __syncthreads();
    for (int idx = t; idx < D * D; idx += 256) {
        int i = idx >> 6, j = idx & 63;
        float acc = 0.0f;
        int km = min(i, j);
        for (int k = 0; k <= km; ++k) acc += Ls[i * D + k] * Us[k * D + j];
        At[(l * D + j) * D + i] = acc;   // transposed store
    }
    if (l == 0) {
        float s = 0.0f;
        for (int i = t; i < NL * D; i += 256)
            s += __logf(softplusf(udiag[i]) + 0.001f);
#pragma unroll
        for (int off = 32; off; off >>= 1) s += __shfl_xor(s, off);
        if ((t & 63) == 0) red[t >> 6] = s;
        __syncthreads();
        if (t == 0) lu_const[0] = red[0] + red[1] + red[2] + red[3];
    }
}

// ---------------- init: copy x, zero logdet ----------------------------------
__global__ void init_kernel(const float* __restrict__ inp, float* __restrict__ x,
                            float* __restrict__ logdet) {
    int i = blockIdx.x * 256 + threadIdx.x;
    if (i < BATCH * D) x[i] = inp[i];
    if (i < BATCH) logdet[i] = 0.0f;
}

// ---------------- MFMA GEMM (G1/G2, all layers batched via grid.y) -----------
template<int RELU>
__global__ __launch_bounds__(256) void gemm_bf16(
    const u16* __restrict__ A0, const u16* __restrict__ Bt0,
    const float* __restrict__ bias0, u16* __restrict__ Cv0,
    int N, int K, int ncol, size_t sA, size_t sB, size_t sb, size_t sC)
{
    __shared__ u16 lds[16384];
    const int ly = blockIdx.y;
    const u16* A = A0 + (size_t)ly * sA;
    const u16* Bt = Bt0 + (size_t)ly * sB;
    const float* bias = bias0 + (size_t)ly * sb;
    u16* Cv = Cv0 + (size_t)ly * sC;
    const int t = threadIdx.x;
    const int w = t >> 6, l = t & 63;
    const int wm = w >> 1, wn = w & 1;
    const int wg = xcd_swz(blockIdx.x, gridDim.x);
    const size_t m0 = (size_t)(wg / ncol) * 128;
    const int n0 = (wg % ncol) * 128;
    const int lrow = l & 15, lk = l >> 4;
    const int srow = l >> 3, sslot = l & 7;

    f32x4 acc[4][4] = {};

    for (int k0 = 0; k0 < K; k0 += 64) {
#pragma unroll
        for (int q = 0; q < 4; ++q) {
            int c = q * 4 + w;
            int row = c * 8 + srow;
            int slog = sslot ^ (row & 7);
            gload16(A + (m0 + row) * K + k0 + slog * 8, &lds[c * 512]);
        }
#pragma unroll
        for (int q = 0; q < 4; ++q) {
            int c = q * 4 + w;
            int row = c * 8 + srow;
            int slog = sslot ^ (row & 7);
            gload16(Bt + (size_t)(n0 + row) * K + k0 + slog * 8, &lds[8192 + c * 512]);
        }
        __syncthreads();
#pragma unroll
        for (int ks = 0; ks < 2; ++ks) {
            bf16x8 a[4], b[4];
#pragma unroll
            for (int mf = 0; mf < 4; ++mf) {
                int row = wm * 64 + mf * 16 + lrow;
                int slot = (ks * 4 + lk) ^ (row & 7);
                a[mf] = *(const bf16x8*)&lds[row * 64 + slot * 8];
            }
#pragma unroll
            for (int nf = 0; nf < 4; ++nf) {
                int row = wn * 64 + nf * 16 + lrow;
                int slot = (ks * 4 + lk) ^ (row & 7);
                b[nf] = *(const bf16x8*)&lds[8192 + row * 64 + slot * 8];
            }
#pragma unroll
            for (int mf = 0; mf < 4; ++mf)
#pragma unroll
                for (int nf = 0; nf < 4; ++nf)
                    acc[mf][nf] = __builtin_amdgcn_mfma_f32_16x16x32_bf16(
                        a[mf], b[nf], acc[mf][nf], 0, 0, 0);
        }
        __syncthreads();
    }
#pragma unroll
    for (int nf = 0; nf < 4; ++nf) {
        int col = n0 + wn * 64 + nf * 16 + lrow;
        float bv = bias[col];
#pragma unroll
        for (int mf = 0; mf < 4; ++mf) {
            size_t rbase = m0 + wm * 64 + mf * 16 + lk * 4;
#pragma unroll
            for (int i = 0; i < 4; ++i) {
                float v = acc[mf][nf][i] + bv;
                if (RELU) v = fmaxf(v, 0.0f);
                Cv[(rbase + i) * N + col] = f2bf(v);
            }
        }
    }
}

// ---------------- spline helpers (register-only) -----------------------------
__device__ __forceinline__ f32x8 cumb(f32x8 p) {
    float m = fmaxf(fmaxf(fmaxf(p[0], p[1]), fmaxf(p[2], p[3])),
                    fmaxf(fmaxf(p[4], p[5]), fmaxf(p[6], p[7])));
    f32x8 e;
    float s = 0.0f;
#pragma unroll
    for (int i = 0; i < 8; ++i) { e[i] = __expf(p[i] - m); s += e[i]; }
    float tt = 0.992f * frcp(s);
    f32x8 c;
    float run = 0.0f;
#pragma unroll
    for (int i = 0; i < 7; ++i) {
        run = fmaf(tt, e[i], run + 0.001f);
        c[i] = fmaf(10.0f, run, -5.0f);
    }
    c[7] = 5.0f;
    return c;
}

__device__ __forceinline__ void rqs_v(float xv, f32x8 uw, f32x8 uh, f32x8 ud,
                                      float& yo, float& ldo) {
    f32x8 cw = cumb(uw);
    f32x8 ch = cumb(uh);
    f32x8 dv;
#pragma unroll
    for (int i = 0; i < 7; ++i) dv[i] = 0.001f + softplus_fast(ud[i]);
    float xc = fminf(fmaxf(xv, -5.0f), 5.0f);
    float icw = -5.0f, icw1 = cw[0], ich = -5.0f, ich1 = ch[0];
    float d0 = 1.0f, d1 = dv[0];
#pragma unroll
    for (int k = 1; k < 8; ++k) {
        bool sel = (xc >= cw[k - 1]);
        icw  = sel ? cw[k - 1] : icw;
        icw1 = sel ? cw[k]     : icw1;
        ich  = sel ? ch[k - 1] : ich;
        ich1 = sel ? ch[k]     : ich1;
        d0   = sel ? dv[k - 1] : d0;
        d1   = sel ? ((k < 7) ? dv[k] : 1.0f) : d1;
    }
    float iw  = icw1 - icw;
    float ih  = ich1 - ich;
    float riw = frcp(iw);
    float dlt = ih * riw;
    float th  = (xc - icw) * riw;
    float omt = 1.0f - th;
    float tomt = th * omt;
    float numer = ih * (dlt * th * th + d0 * tomt);
    float den = dlt + (d0 + d1 - 2.0f * dlt) * tomt;
    float rden = frcp(den);
    float outv = ich + numer * rden;
    float dnum = dlt * dlt * (d1 * th * th + 2.0f * dlt * tomt + d0 * omt * omt);
    float ld = __logf(dnum * rden * rden);
    bool inside = (xv >= -5.0f) && (xv <= 5.0f);
    yo  = inside ? outv : xv;
    ldo = inside ? ld : 0.0f;
}

// ---------------- FUSED v2: GEMM3 (staged hh2, deep W3t hoist) + spline + LU --
// Block: 64 rows, 512 thr (8 waves). hh2 tile (64x256) staged ONCE via gload16
// in gemm-layout (512B rows, XOR slots -> measured-0-conflict read pattern).
// Per chunk (16 dims, 384 cols): wave w owns cols w*48..+47 (3 mf), all 64 rows
// (4 rf). Full ks unroll -> compiler hoists the 24 W3t L2-loads across MFMAs.
// Epilogue packs 4 consecutive param cols per lane -> 8B LDS write -> spline
// (2 pairs/thread) -> LU. Params never touch HBM.
__global__ __launch_bounds__(512, 2) void gemm3_spline_lu(
    const u16* __restrict__ hh2,     // [BATCH][256] bf16 (layer slab)
    const u16* __restrict__ W3t,     // [1536][256] bf16 (layer slab)
    const float* __restrict__ b3p,   // [1536] padded bias (layer slab)
    const float* __restrict__ At, const float* __restrict__ lu_bias,
    float* __restrict__ x, float* __restrict__ logdet, int lay)
{
    __shared__ u16 hh2_s[FROWS * 256];       // 32 KB
    __shared__ u16 params_s[FROWS * PPAD];   // 50176 B
    __shared__ float y_s[FROWS * 65];        // 16640 B
    __shared__ float ld_s[FROWS];
    const int t = threadIdx.x;
    const int w = t >> 6, ln = t & 63;
    const int lr = ln & 15, lk = ln >> 4;
    const int rbase = blockIdx.x * FROWS;

    // stage hh2 64x256 via gload16; source pre-swizzled (slot ^= row&7 per kb)
#pragma unroll
    for (int r = 0; r < 4; ++r) {
        int basec = (r * 8 + w) * 64;        // 16B-chunk base for this wave
        int c = basec + ln;
        int row = c >> 5, rem = c & 31;
        int kb = rem >> 3, sl = rem & 7;
        gload16(hh2 + (size_t)(rbase + row) * HID + kb * 64 + (sl ^ (row & 7)) * 8,
                &hh2_s[basec * 8]);
    }
    if (t < FROWS) ld_s[t] = 0.0f;
    __syncthreads();   // implies vmcnt drain

    float ld_acc = 0.0f;
    const int srow = t & 63, sd0 = t >> 6;   // spline: row = lane, dims sd0/sd0+8

    for (int ch = 0; ch < NCH; ++ch) {
        // prefetch this chunk's x values (hidden under the MFMA phase)
        float xv0 = x[(size_t)(rbase + srow) * D + ch * 16 + sd0];
        float xv1 = x[(size_t)(rbase + srow) * D + ch * 16 + sd0 + 8];

        // ---- MFMA phase (barrier-free): W as A-operand, hh2 as B-operand ----
        f32x4 acc[3][4] = {};
        const u16* wb = W3t + (size_t)(ch * CPC + w * 48 + lr) * HID + lk * 8;
#pragma unroll
        for (int ks = 0; ks < 8; ++ks) {
            bf16x8 hf[4];
#pragma unroll
            for (int rf = 0; rf < 4; ++rf) {
                int row = rf * 16 + lr;
                hf[rf] = *(const bf16x8*)&hh2_s[row * 256 + (ks >> 1) * 64
                              + ((((ks & 1) * 4) + lk) ^ (lr & 7)) * 8];
            }
#pragma unroll
            for (int mf = 0; mf < 3; ++mf) {
                bf16x8 wf = *(const bf16x8*)(wb + (size_t)mf * 16 * HID + ks * 32);
#pragma unroll
                for (int rf = 0; rf < 4; ++rf)
                    acc[mf][rf] = __builtin_amdgcn_mfma_f32_16x16x32_bf16(
                        wf, hf[rf], acc[mf][rf], 0, 0, 0);
            }
        }
        __syncthreads();   // all waves done reading params_s (prev chunk spline)

        // ---- epilogue: bias + pack 4 consecutive cols -> 8B LDS write ----
        {
            const float* bb = b3p + ch * CPC + w * 48 + 4 * lk;
#pragma unroll
            for (int mf = 0; mf < 3; ++mf) {
                float4 bv = *(const float4*)(bb + mf * 16);
#pragma unroll
                for (int rf = 0; rf < 4; ++rf) {
                    f32x4 v = acc[mf][rf];
                    unsigned int lo = (unsigned int)f2bf(v[0] + bv.x)
                                    | ((unsigned int)f2bf(v[1] + bv.y) << 16);
                    unsigned int hi = (unsigned int)f2bf(v[2] + bv.z)
                                    | ((unsigned int)f2bf(v[3] + bv.w) << 16);
                    uint2 pv; pv.x = lo; pv.y = hi;
                    int r = rf * 16 + lr;
                    int cbase = w * 48 + mf * 16 + 4 * lk;
                    *(uint2*)&params_s[r * PPAD + cbase] = pv;
                }
            }
        }
        __syncthreads();   // params ready

        // ---- spline: 2 (row, dim) pairs per thread ----
#pragma unroll
        for (int pr = 0; pr < 2; ++pr) {
            int dg = ch * 16 + sd0 + pr * 8;
            const u16x8* pp = (const u16x8*)&params_s[srow * PPAD + (sd0 + pr * 8) * PPDP];
            u16x8 q0 = pp[0], q1 = pp[1], q2 = pp[2];
            f32x8 uw, uh, ud;
#pragma unroll
            for (int j = 0; j < 8; ++j) {
                uw[j] = bf2f(q0[j]);
                uh[j] = bf2f(q1[j]);
                ud[j] = bf2f(q2[j]);
            }
            float xv = pr ? xv1 : xv0;
            float y, ldv;
            rqs_v(xv, uw, uh, ud, y, ldv);
            y_s[srow * 65 + dg] = y;
            ld_acc += ldv;
        }
        // no barrier: next chunk's pre-epilogue barrier protects params_s
    }

    atomicAdd(&ld_s[srow], ld_acc);
    __syncthreads();
    if (t < FROWS) logdet[rbase + t] += ld_s[t];

    // ---- LU: x_new[r][i] = sum_j y[r][j]*A[i][j] + bias[i] ----
#pragma unroll
    for (int p = 0; p < 8; ++p) {
        int idx = p * 512 + t;
        int r = idx >> 6, i = idx & 63;
        float acc2 = lu_bias[lay * D + i];
        const float* ap = At + (size_t)lay * D * D + i;
#pragma unroll 8
        for (int j = 0; j < D; ++j)
            acc2 = fmaf(y_s[r * 65 + j], ap[j * D], acc2);
        x[(size_t)(rbase + r) * D + i] = acc2;
    }
}

// ---------------- final: out = base + logdet ---------------------------------
__global__ void final_kernel(const float* __restrict__ x,
                             const float* __restrict__ logdet,
                             const float* __restrict__ lu_const,
                             float* __restrict__ out) {
    int t = threadIdx.x;
    int b = blockIdx.x * 4 + (t >> 6);
    int d = t & 63;
    float v = x[(size_t)b * D + d];
    float s = v * v;
#pragma unroll
    for (int off = 32; off; off >>= 1) s += __shfl_xor(s, off);
    if (d == 0)
        out[b] = logdet[b] + lu_const[0] - 0.5f * s - 0.5f * 64.0f * 1.8378770664093453f;
}

extern "C" void kernel_launch(void* const* d_in, const int* in_sizes, int n_in,
                              void* d_out, int out_size, void* d_ws, size_t ws_size,
                              hipStream_t stream) {
    const float* inputs  = (const float*)d_in[0];
    const float* context = (const float*)d_in[1];
    const float* W1      = (const float*)d_in[2];
    const float* b1      = (const float*)d_in[3];
    const float* W2      = (const float*)d_in[4];
    const float* b2      = (const float*)d_in[5];
    const float* W3      = (const float*)d_in[6];
    const float* b3      = (const float*)d_in[7];
    const float* lu_bias = (const float*)d_in[8];
    const float* lower_e = (const float*)d_in[9];
    const float* upper_e = (const float*)d_in[10];
    const float* udiag   = (const float*)d_in[11];
    float* out = (float*)d_out;

    char* p = (char*)d_ws;
    auto alloc = [&](size_t bytes) { void* r = p; p += (bytes + 255) & ~(size_t)255; return r; };
    float* x        = (float*)alloc((size_t)BATCH * D * 4);
    float* logdet   = (float*)alloc((size_t)BATCH * 4);
    float* At       = (float*)alloc((size_t)NL * D * D * 4);
    float* lu_const = (float*)alloc(256);
    u16*   ctx_bf   = (u16*)alloc((size_t)BATCH * CDIM * 2);
    u16*   hh1      = (u16*)alloc((size_t)NL * BATCH * HID * 2);   // all layers
    u16*   hh2      = (u16*)alloc((size_t)NL * BATCH * HID * 2);   // all layers
    u16*   W1t      = (u16*)alloc((size_t)NL * HID * CDIM * 2);
    u16*   W2t      = (u16*)alloc((size_t)NL * HID * HID * 2);
    u16*   W3t      = (u16*)alloc((size_t)NL * NPAD * HID * 2);
    float* b3p      = (float*)alloc((size_t)NL * NPAD * 4);

    cvt_ctx<<<(BATCH * CDIM + 255) / 256, 256, 0, stream>>>(context, ctx_bf);
    prep_w12<<<(NL * HID * HID + 255) / 256, 256, 0, stream>>>(W1, W2, W1t, W2t);
    prep_w3<<<(NL * NPAD * HID + 255) / 256, 256, 0, stream>>>(W3, b3, W3t, b3p);
    lu_prep<<<NL, 256, 0, stream>>>(lower_e, upper_e, udiag, At, lu_const);
    init_kernel<<<(BATCH * D + 255) / 256, 256, 0, stream>>>(inputs, x, logdet);

    // conditioner depends only on context: batch all layers' G1, then all G2
    dim3 gmlp((BATCH / 128) * 2, NL);
    gemm_bf16<1><<<gmlp, 256, 0, stream>>>(
        ctx_bf, W1t, b1, hh1, HID, CDIM, 2,
        0, (size_t)HID * CDIM, HID, (size_t)BATCH * HID);
    gemm_bf16<1><<<gmlp, 256, 0, stream>>>(
        hh1, W2t, b2, hh2, HID, HID, 2,
        (size_t)BATCH * HID, (size_t)HID * HID, HID, (size_t)BATCH * HID);

    for (int lay = 0; lay < NL; ++lay) {
        gemm3_spline_lu<<<BATCH / FROWS, 512, 0, stream>>>(
            hh2 + (size_t)lay * BATCH * HID,
            W3t + (size_t)lay * NPAD * HID, b3p + (size_t)lay * NPAD,
            At, lu_bias, x, logdet, lay);
    }
    final_kernel<<<BATCH / 4, 256, 0, stream>>>(x, logdet, lu_const, out);
}